// Round 4
// baseline (624.119 us; speedup 1.0000x reference)
//
#include <hip/hip_runtime.h>

#define CC 85
#define NC 80
#define MAXGT 20
#define BSZ 64
#define IGNORE_T 0.5f
#define CHUNK 1024
#define NCHMAX 8

// rows per sample per scale: 3*lsz*lsz
#define N0 507
#define N1 2028
#define N2 8112
#define RR0 (BSZ*N0)   /* 32448  */
#define RR1 (BSZ*N1)   /* 129792 */
#define RR2 (BSZ*N2)   /* 519168 */

// float4 count per target buffer (rows*85 floats, always divisible by 4)
#define F0 ((RR0*CC)/4)   /* 689,520    */
#define F1 ((RR1*CC)/4)   /* 2,758,080  */
#define F2 ((RR2*CC)/4)   /* 11,032,320 */

// ws layout (bytes). Only cnt+done need zero-init (1536 B memset).
// Everything else is written before being read within this call.
#define CNT_OFF  0u                        /* int cnt[192]            */
#define DONE_OFF 768u                      /* int done[192]           */
#define ZERO_B   1536u
#define POS_OFF  1536u                     /* int pos[192][20]        */
#define POS_B    (192u*MAXGT*4u)           /* 15360                   */
#define KEY_OFF  (POS_OFF+POS_B)           /* 16896 (8-aligned)       */
#define KEY_B    (192u*NCHMAX*MAXGT*8u)    /* u64 keys[192][8][20]    */
#define NOB_OFF  (KEY_OFF+KEY_B)           /* float nob[192][8]       */

// ANCH_REV[l] = ANCHORS[2-l]
__constant__ float d_anch[3][3][2] = {
  {{0.2788f,0.2163f},{0.375f,0.476f},{0.8966f,0.7837f}},  // scale 0, lsz=13
  {{0.0721f,0.1466f},{0.149f,0.1082f},{0.1418f,0.2861f}}, // scale 1, lsz=26
  {{0.024f,0.0313f},{0.0385f,0.0721f},{0.0793f,0.0553f}}, // scale 2, lsz=52
};

__device__ __forceinline__ float sigmoidf(float x){ return 1.0f/(1.0f+__expf(-x)); }
__device__ __forceinline__ float bcef(float p, float t){
  p = fminf(fmaxf(p, 1e-7f), 1.0f-1e-7f);
  return -t*__logf(p) - (1.0f-t)*__logf(1.0f-p);
}

// ---- kernel 0: fully-coalesced streaming conf scan. Each float4 covers
// elems [4i,4i+4); conf elems sit at (e mod 85)==4, so at most ONE per
// load: present iff m=(4i mod 85) in [1,4], at component 4-m, row = e/85.
// 232 MB coalesced beats the old 340B-strided sector gather.
template<int NROWS, int S, int NF>
__device__ __forceinline__ void scan_stream(const float4* __restrict__ T,
                                            int* __restrict__ cnt,
                                            int* __restrict__ pos,
                                            int gtid, int gstr)
{
  for (int i = gtid; i < NF; i += gstr){
    const float4 v = T[i];
    const unsigned e = 4u*(unsigned)i;
    const unsigned q = e / 85u;            // const-div -> magic mul
    const unsigned m = e - q*85u;
    if (m - 1u < 4u){                      // m in [1,4]
      const float c = (m==4u) ? v.x : (m==3u) ? v.y : (m==2u) ? v.z : v.w;
      if (c > 0.5f){
        const unsigned b = q / (unsigned)NROWS;   // const-div
        const unsigned n = q - b*(unsigned)NROWS; // row within sample
        const int slot = S*BSZ + (int)b;
        const int idx = atomicAdd(&cnt[slot], 1);
        if (idx < MAXGT) pos[slot*MAXGT + idx] = (int)n;
      }
    }
  }
}

__global__ __launch_bounds__(256)
void k_scan(const float4* __restrict__ t0, const float4* __restrict__ t1,
            const float4* __restrict__ t2,
            int* __restrict__ cnt, int* __restrict__ pos,
            float* __restrict__ out)
{
  const int gtid = blockIdx.x*256 + threadIdx.x;
  const int gstr = gridDim.x*256;
  if (gtid == 0) out[0] = 0.0f;           // zeroed before k_ioufinal's atomics
  scan_stream<N0,0,F0>(t0, cnt, pos, gtid, gstr);
  scan_stream<N1,1,F1>(t1, cnt, pos, gtid, gstr);
  scan_stream<N2,2,F2>(t2, cnt, pos, gtid, gstr);
}

// ---- kernel 1: per-chunk inline decode + 20-way IoU argmax + noobj; the
// LAST chunk-block per slot (fence + done-counter, no spinning) reduces the
// chunk keys and computes reg/conf/cls + deduped noobj correction, then
// atomicAdd's the slot loss to out. 3 dispatches total for the whole op.
// __launch_bounds__(256,2): key[20] (40 VGPR) must stay in registers.
template<int LSZ, int S, int NCH>
__device__ __forceinline__ void iou_final_one(
    const float* __restrict__ pred, const float* __restrict__ tgt,
    int b, int chunk,
    const int* __restrict__ cnt, const int* __restrict__ pos,
    unsigned long long* __restrict__ keys, float* __restrict__ nob,
    int* __restrict__ done, float* __restrict__ out)
{
  constexpr int L2 = LSZ*LSZ, N = 3*L2;
  if (chunk >= NCH) return;                // uniform; inert blocks exit early
  const int slot = S*BSZ + b;
  const float* P = pred + (size_t)b*3*CC*L2;
  const float* T = tgt  + (size_t)b*N*CC;
  const int tid = threadIdx.x;
  __shared__ float4 tb[MAXGT];
  __shared__ float  area[MAXGT];
  __shared__ float  gx[MAXGT], gy[MAXGT], gw[MAXGT], gh[MAXGT];
  __shared__ int    gp[MAXGT];
  __shared__ unsigned long long lkey[4][MAXGT];
  __shared__ float  lnob[4];
  __shared__ int    bn[MAXGT];
  __shared__ float  wsum[4];
  __shared__ int    sLast;
  const int G = min(cnt[slot], MAXGT);
  if (tid < MAXGT){
    float x=0.f,y=0.f,w=0.f,h=0.f; int p=0;
    if (tid < G){
      p = pos[slot*MAXGT+tid];
      const float* r = T + (size_t)p*CC;
      x=r[0]; y=r[1]; w=r[2]; h=r[3];
    }
    gp[tid]=p; gx[tid]=x; gy[tid]=y; gw[tid]=w; gh[tid]=h;
    tb[tid]   = make_float4(x-w*0.5f, y-h*0.5f, x+w*0.5f, y+h*0.5f);
    area[tid] = w*h;                       // zero filler box -> iou==0 (gmask)
  }
  __syncthreads();

  unsigned long long key[MAXGT];
  #pragma unroll
  for (int g=0; g<MAXGT; g++) key[g]=0ull;
  float noobj = 0.0f;
  const float inv = 1.0f/(float)LSZ;
  const int n0 = chunk*CHUNK;
  const int nend = min(n0+CHUNK, N);
  for (int n = n0+tid; n < nend; n += 256){
    const int a = n/L2, rem = n - a*L2, ii = rem/LSZ, jj = rem - ii*LSZ;
    const float* bp = P + (size_t)a*CC*L2 + rem;     // coalesced per channel
    const float q0=bp[0], q1=bp[L2], q2=bp[2*L2], q3=bp[3*L2], q4=bp[4*L2];
    const float px = ((float)jj + sigmoidf(q0))*inv;
    const float py = ((float)ii + sigmoidf(q1))*inv;
    const float pw = d_anch[S][a][0]*__expf(q2);
    const float ph = d_anch[S][a][1]*__expf(q3);
    const float x0=px-pw*0.5f, x1=px+pw*0.5f, y0=py-ph*0.5f, y1=py+ph*0.5f;
    const float pa = pw*ph;
    float maxi = 0.0f;
    const unsigned long long nin = (unsigned long long)(~(unsigned)n); // tie: first
    #pragma unroll
    for (int g=0; g<MAXGT; g++){
      const float4 t4 = tb[g];             // broadcast ds_read_b128
      const float w = fmaxf(fminf(t4.z,x1) - fmaxf(t4.x,x0), 0.0f);
      const float h = fmaxf(fminf(t4.w,y1) - fmaxf(t4.y,y0), 0.0f);
      const float inter = w*h;
      const float io = inter / fmaxf(area[g]+pa-inter, 1e-6f);
      maxi = fmaxf(maxi, io);
      const unsigned long long k =
        ((unsigned long long)__float_as_uint(io)<<32) | nin;
      if (k > key[g]) key[g] = k;
    }
    if (maxi < IGNORE_T) noobj += bcef(sigmoidf(q4), 0.0f);
  }
  const int wid = tid>>6, lane = tid&63;
  #pragma unroll
  for (int g=0; g<MAXGT; g++){
    unsigned long long k = key[g];
    for (int off=32; off>0; off>>=1){
      const unsigned long long o = __shfl_down(k, off, 64);
      if (o > k) k = o;
    }
    if (lane==0) lkey[wid][g] = k;
  }
  for (int off=32; off>0; off>>=1) noobj += __shfl_down(noobj, off, 64);
  if (lane==0) lnob[wid] = noobj;
  __syncthreads();
  if (tid < MAXGT){
    unsigned long long k = lkey[0][tid];
    #pragma unroll
    for (int w=1; w<4; w++){ const unsigned long long o = lkey[w][tid]; if (o>k) k=o; }
    keys[((size_t)slot*NCHMAX + chunk)*MAXGT + tid] = k;
  }
  if (tid==0) nob[slot*NCHMAX + chunk] = lnob[0]+lnob[1]+lnob[2]+lnob[3];

  // ---- last-block election: release writes, then count arrivals
  __threadfence();                         // device-scope release of keys/nob
  __syncthreads();                         // all fences precede the atomic
  if (tid==0) sLast = (atomicAdd(&done[slot], 1) == NCH-1) ? 1 : 0;
  __syncthreads();
  if (!sLast) return;                      // uniform
  __threadfence();                         // acquire before reading peers' data

  // ---- final phase (exactly one block per slot reaches here) ----
  if (tid < MAXGT){
    unsigned long long k = keys[((size_t)slot*NCHMAX)*MAXGT + tid];
    #pragma unroll
    for (int c=1; c<NCH; c++){
      const unsigned long long o = keys[((size_t)slot*NCHMAX + c)*MAXGT + tid];
      if (o > k) k = o;
    }
    bn[tid] = (int)(~(unsigned)(k & 0xffffffffull));
  }
  __syncthreads();
  float loss = 0.0f;
  if (tid < G){
    const int n = bn[tid];
    const int a = n/L2, rem = n - a*L2, i = rem/LSZ, j = rem - i*LSZ;
    const float* bp = P + (size_t)a*CC*L2 + rem;
    const float q0=bp[0], q1=bp[L2], q2=bp[2*L2], q3=bp[3*L2], q4=bp[4*L2];
    const float px = ((float)j + sigmoidf(q0))*inv;
    const float py = ((float)i + sigmoidf(q1))*inv;
    const float pw = d_anch[S][a][0]*__expf(q2);
    const float ph = d_anch[S][a][1]*__expf(q3);
    const float dx=px-gx[tid], dy=py-gy[tid], dw=pw-gw[tid], dh=ph-gh[tid];
    loss += (dx*dx+dy*dy+dw*dw+dh*dh)*(2.0f - gw[tid]*gh[tid]);   // reg
    loss += bcef(sigmoidf(q4), 1.0f);                              // conf(obj)
    // subtract bce(conf,0) once per UNIQUE best index (counted in noobj)
    bool first = true;
    for (int g2=0; g2<tid; g2++) if (bn[g2]==n) first=false;
    if (first){
      const float bx0=px-pw*0.5f, bx1=px+pw*0.5f, by0=py-ph*0.5f, by1=py+ph*0.5f;
      const float parea = pw*ph;
      float maxiou = 0.0f;
      for (int g2=0; g2<MAXGT; g2++){
        const float4 t4 = tb[g2];
        const float w = fmaxf(fminf(t4.z,bx1) - fmaxf(t4.x,bx0), 0.0f);
        const float h = fmaxf(fminf(t4.w,by1) - fmaxf(t4.y,by0), 0.0f);
        const float inter = w*h;
        maxiou = fmaxf(maxiou, inter / fmaxf(area[g2]+parea-inter, 1e-6f));
      }
      if (maxiou < IGNORE_T) loss -= bcef(sigmoidf(q4), 0.0f);
    }
  }
  if (tid==0){
    #pragma unroll
    for (int c=0; c<NCH; c++) loss += nob[slot*NCHMAX + c];
  }
  // class loss: up to 1600 scattered gathers over 256 threads (~7 rounds)
  for (int idx = tid; idx < G*NC; idx += 256){
    const int g = idx/NC, c = idx - g*NC;
    const int n = bn[g];
    const int a = n/L2, rem = n - a*L2;
    const float q  = P[(size_t)a*CC*L2 + (size_t)(5+c)*L2 + rem];
    const float tc = T[(size_t)gp[g]*CC + 5 + c];
    loss += bcef(sigmoidf(q), tc);
  }
  for (int off=32; off>0; off>>=1) loss += __shfl_down(loss, off, 64);
  if (lane==0) wsum[wid] = loss;
  __syncthreads();
  if (tid==0) atomicAdd(out, wsum[0]+wsum[1]+wsum[2]+wsum[3]);
}

__global__ __launch_bounds__(256, 2)
void k_ioufinal(const float* __restrict__ p0, const float* __restrict__ t0,
                const float* __restrict__ p1, const float* __restrict__ t1,
                const float* __restrict__ p2, const float* __restrict__ t2,
                const int* __restrict__ cnt, const int* __restrict__ pos,
                unsigned long long* __restrict__ keys, float* __restrict__ nob,
                int* __restrict__ done, float* __restrict__ out)
{
  const int chunk = blockIdx.x, b = blockIdx.y, s = blockIdx.z;
  if (s==0)      iou_final_one<13,0,1>(p0, t0, b, chunk, cnt, pos, keys, nob, done, out);
  else if (s==1) iou_final_one<26,1,2>(p1, t1, b, chunk, cnt, pos, keys, nob, done, out);
  else           iou_final_one<52,2,8>(p2, t2, b, chunk, cnt, pos, keys, nob, done, out);
}

extern "C" void kernel_launch(void* const* d_in, const int* in_sizes, int n_in,
                              void* d_out, int out_size, void* d_ws, size_t ws_size,
                              hipStream_t stream)
{
  // setup_inputs() dict order: pred0, targets0, pred1, targets1, pred2, targets2
  const float* p0 = (const float*)d_in[0];
  const float* t0 = (const float*)d_in[1];
  const float* p1 = (const float*)d_in[2];
  const float* t1 = (const float*)d_in[3];
  const float* p2 = (const float*)d_in[4];
  const float* t2 = (const float*)d_in[5];
  char* ws = (char*)d_ws;
  int*                ws_cnt  = (int*)(ws + CNT_OFF);
  int*                ws_done = (int*)(ws + DONE_OFF);
  int*                ws_pos  = (int*)(ws + POS_OFF);
  unsigned long long* ws_keys = (unsigned long long*)(ws + KEY_OFF);
  float*              ws_nob  = (float*)(ws + NOB_OFF);
  float*              out     = (float*)d_out;

  hipMemsetAsync(ws, 0, ZERO_B, stream);              // cnt + done only

  k_scan<<<2048, 256, 0, stream>>>((const float4*)t0, (const float4*)t1,
                                   (const float4*)t2, ws_cnt, ws_pos, out);
  k_ioufinal<<<dim3(NCHMAX,BSZ,3), 256, 0, stream>>>(p0,t0,p1,t1,p2,t2,
                                                     ws_cnt, ws_pos, ws_keys,
                                                     ws_nob, ws_done, out);
}

// Round 5
// 411.809 us; speedup vs baseline: 1.5156x; 1.5156x over previous
//
#include <hip/hip_runtime.h>

#define CC 85
#define NC 80
#define MAXGT 20
#define BSZ 64
#define IGNORE_T 0.5f
#define CHUNK 1024
#define NCHMAX 8

// rows per sample per scale: 3*lsz*lsz
#define N0 507
#define N1 2028
#define N2 8112
#define RR0 (BSZ*N0)   /* 32448  */
#define RR1 (BSZ*N1)   /* 129792 */
#define RR2 (BSZ*N2)   /* 519168 */

// float4 count per target buffer (rows*85 floats, always divisible by 4)
#define F0 ((RR0*CC)/4)   /* 689,520    */
#define F1 ((RR1*CC)/4)   /* 2,758,080  */
#define F2 ((RR2*CC)/4)   /* 11,032,320 */

// ws layout (bytes). Only cnt needs zero-init (768 B memset). Everything
// else is written unconditionally before being read (poison-proof).
// NO device-scope fences anywhere: inter-kernel ordering is stream order.
#define CNT_B    (192u*4u)                 /* int cnt[192]                  */
#define POS_OFF  CNT_B                     /* int pos[192][20]              */
#define POS_B    (192u*MAXGT*4u)
#define KEY_OFF  (POS_OFF+POS_B)           /* u64 keys[192][8][20], 8-align */
#define KEY_B    (192u*NCHMAX*MAXGT*8u)
#define NOB_OFF  (KEY_OFF+KEY_B)           /* float nob[192][8]             */
#define NOB_B    (192u*NCHMAX*4u)
#define PART_OFF (NOB_OFF+NOB_B)           /* float part[192][2]            */

// ANCH_REV[l] = ANCHORS[2-l]
__constant__ float d_anch[3][3][2] = {
  {{0.2788f,0.2163f},{0.375f,0.476f},{0.8966f,0.7837f}},  // scale 0, lsz=13
  {{0.0721f,0.1466f},{0.149f,0.1082f},{0.1418f,0.2861f}}, // scale 1, lsz=26
  {{0.024f,0.0313f},{0.0385f,0.0721f},{0.0793f,0.0553f}}, // scale 2, lsz=52
};

__device__ __forceinline__ float sigmoidf(float x){ return 1.0f/(1.0f+__expf(-x)); }
__device__ __forceinline__ float bcef(float p, float t){
  p = fminf(fmaxf(p, 1e-7f), 1.0f-1e-7f);
  return -t*__logf(p) - (1.0f-t)*__logf(1.0f-p);
}

// ---- kernel 0: fully-coalesced streaming conf scan (R4-proven). Each
// float4 covers elems [4i,4i+4); conf elems sit at (e mod 85)==4, so at
// most ONE per load: present iff m=(4i mod 85) in [1,4], at comp 4-m.
template<int NROWS, int S, int NF>
__device__ __forceinline__ void scan_stream(const float4* __restrict__ T,
                                            int* __restrict__ cnt,
                                            int* __restrict__ pos,
                                            int gtid, int gstr)
{
  for (int i = gtid; i < NF; i += gstr){
    const float4 v = T[i];
    const unsigned e = 4u*(unsigned)i;
    const unsigned q = e / 85u;            // const-div -> magic mul
    const unsigned m = e - q*85u;
    if (m - 1u < 4u){                      // m in [1,4]
      const float c = (m==4u) ? v.x : (m==3u) ? v.y : (m==2u) ? v.z : v.w;
      if (c > 0.5f){
        const unsigned b = q / (unsigned)NROWS;   // const-div
        const unsigned n = q - b*(unsigned)NROWS; // row within sample
        const int slot = S*BSZ + (int)b;
        const int idx = atomicAdd(&cnt[slot], 1);
        if (idx < MAXGT) pos[slot*MAXGT + idx] = (int)n;
      }
    }
  }
}

__global__ __launch_bounds__(256)
void k_scan(const float4* __restrict__ t0, const float4* __restrict__ t1,
            const float4* __restrict__ t2,
            int* __restrict__ cnt, int* __restrict__ pos)
{
  const int gtid = blockIdx.x*256 + threadIdx.x;
  const int gstr = gridDim.x*256;
  scan_stream<N0,0,F0>(t0, cnt, pos, gtid, gstr);
  scan_stream<N1,1,F1>(t1, cnt, pos, gtid, gstr);
  scan_stream<N2,2,F2>(t2, cnt, pos, gtid, gstr);
}

// ---- kernel 1: inline decode + 20-way IoU argmax keys + noobj per 1024-row
// chunk. No atomics, NO FENCES (R4 lesson: device-scope __threadfence on
// non-coherent-XCD gfx950 = L2 flush storm, +290us). Each chunk-block owns
// keys[slot][chunk][*], nob[slot][chunk]; k_final (next dispatch) reduces.
// __launch_bounds__(256,2): key[20] (40 VGPR) must stay in registers.
template<int LSZ, int S>
__device__ __forceinline__ void iou_one(const float* __restrict__ pred,
                                        const float* __restrict__ tgt,
                                        int b, int chunk,
                                        const int* __restrict__ cnt,
                                        const int* __restrict__ pos,
                                        unsigned long long* __restrict__ keys,
                                        float* __restrict__ nob){
  constexpr int L2 = LSZ*LSZ, N = 3*L2;
  const int n0 = chunk*CHUNK;
  if (n0 >= N) return;                       // uniform per block
  const int slot = S*BSZ + b;
  const float* P = pred + (size_t)b*3*CC*L2;
  const float* T = tgt  + (size_t)b*N*CC;
  const int tid = threadIdx.x;
  __shared__ float4 tb[MAXGT];
  __shared__ float  area[MAXGT];
  __shared__ unsigned long long lkey[4][MAXGT];
  __shared__ float  lnob[4];
  if (tid < MAXGT){
    int G = min(cnt[slot], MAXGT);
    float x=0.f,y=0.f,w=0.f,h=0.f;
    if (tid < G){
      const float* r = T + (size_t)pos[slot*MAXGT+tid]*CC;
      x=r[0]; y=r[1]; w=r[2]; h=r[3];
    }
    tb[tid]   = make_float4(x-w*0.5f, y-h*0.5f, x+w*0.5f, y+h*0.5f);
    area[tid] = w*h;                         // zero box -> iou==0 (gmask filler)
  }
  __syncthreads();
  unsigned long long key[MAXGT];
  #pragma unroll
  for (int g=0; g<MAXGT; g++) key[g]=0ull;
  float noobj = 0.0f;
  const float inv = 1.0f/(float)LSZ;
  const int nend = min(n0+CHUNK, N);
  for (int n = n0+tid; n < nend; n += 256){
    const int a = n/L2, rem = n - a*L2, ii = rem/LSZ, jj = rem - ii*LSZ;
    const float* bp = P + (size_t)a*CC*L2 + rem;     // coalesced per channel
    const float q0=bp[0], q1=bp[L2], q2=bp[2*L2], q3=bp[3*L2], q4=bp[4*L2];
    const float px = ((float)jj + sigmoidf(q0))*inv;
    const float py = ((float)ii + sigmoidf(q1))*inv;
    const float pw = d_anch[S][a][0]*__expf(q2);
    const float ph = d_anch[S][a][1]*__expf(q3);
    const float x0=px-pw*0.5f, x1=px+pw*0.5f, y0=py-ph*0.5f, y1=py+ph*0.5f;
    const float pa = pw*ph;
    float maxi = 0.0f;
    const unsigned long long nin = (unsigned long long)(~(unsigned)n); // tie: first
    #pragma unroll
    for (int g=0; g<MAXGT; g++){
      const float4 t4 = tb[g];               // broadcast ds_read_b128
      const float w = fmaxf(fminf(t4.z,x1) - fmaxf(t4.x,x0), 0.0f);
      const float h = fmaxf(fminf(t4.w,y1) - fmaxf(t4.y,y0), 0.0f);
      const float inter = w*h;
      const float io = inter / fmaxf(area[g]+pa-inter, 1e-6f);
      maxi = fmaxf(maxi, io);
      const unsigned long long k =
        ((unsigned long long)__float_as_uint(io)<<32) | nin;
      if (k > key[g]) key[g] = k;
    }
    if (maxi < IGNORE_T) noobj += bcef(sigmoidf(q4), 0.0f);
  }
  const int wid = tid>>6, lane = tid&63;
  #pragma unroll
  for (int g=0; g<MAXGT; g++){
    unsigned long long k = key[g];
    for (int off=32; off>0; off>>=1){
      const unsigned long long o = __shfl_down(k, off, 64);
      if (o > k) k = o;
    }
    if (lane==0) lkey[wid][g] = k;
  }
  for (int off=32; off>0; off>>=1) noobj += __shfl_down(noobj, off, 64);
  if (lane==0) lnob[wid] = noobj;
  __syncthreads();
  if (tid < MAXGT){
    unsigned long long k = lkey[0][tid];
    #pragma unroll
    for (int w=1; w<4; w++){ const unsigned long long o = lkey[w][tid]; if (o>k) k=o; }
    keys[((size_t)slot*NCHMAX + chunk)*MAXGT + tid] = k;   // unconditional
  }
  if (tid==0) nob[slot*NCHMAX + chunk] = lnob[0]+lnob[1]+lnob[2]+lnob[3];
}

__global__ __launch_bounds__(256, 2)
void k_iou(const float* __restrict__ p0, const float* __restrict__ t0,
           const float* __restrict__ p1, const float* __restrict__ t1,
           const float* __restrict__ p2, const float* __restrict__ t2,
           const int* __restrict__ cnt, const int* __restrict__ pos,
           unsigned long long* __restrict__ keys, float* __restrict__ nob){
  const int chunk = blockIdx.x, b = blockIdx.y, s = blockIdx.z;
  if (s==0)      iou_one<13,0>(p0, t0, b, chunk, cnt, pos, keys, nob);
  else if (s==1) iou_one<26,1>(p1, t1, b, chunk, cnt, pos, keys, nob);
  else           iou_one<52,2>(p2, t2, b, chunk, cnt, pos, keys, nob);
}

// ---- kernel 2: chunk-max -> bn, then reg/conf/cls + deduped noobj
// correction. z-split x2 spreads the G*80 scattered class gathers.
template<int LSZ, int S, int NCH>
__device__ __forceinline__ void final_one(const float* __restrict__ pred,
                                          const float* __restrict__ tgt,
                                          int b, int z,
                                          const int* __restrict__ cnt,
                                          const int* __restrict__ pos,
                                          const unsigned long long* __restrict__ keys,
                                          const float* __restrict__ nob,
                                          float* __restrict__ part){
  constexpr int L2 = LSZ*LSZ, N = 3*L2;
  const int slot = S*BSZ + b;
  const float* P = pred + (size_t)b*3*CC*L2;
  const float* T = tgt  + (size_t)b*N*CC;
  const int tid = threadIdx.x;
  __shared__ int bn[MAXGT];
  __shared__ int gp[MAXGT];
  __shared__ float gx[MAXGT], gy[MAXGT], gw[MAXGT], gh[MAXGT];
  __shared__ float4 tb[MAXGT];
  __shared__ float area[MAXGT];
  const int G = min(cnt[slot], MAXGT);
  if (tid < MAXGT){
    unsigned long long k = keys[((size_t)slot*NCHMAX + 0)*MAXGT + tid];
    #pragma unroll
    for (int c=1; c<NCH; c++){
      const unsigned long long o = keys[((size_t)slot*NCHMAX + c)*MAXGT + tid];
      if (o > k) k = o;
    }
    bn[tid] = (int)(~(unsigned)(k & 0xffffffffull));
    float x=0.f,y=0.f,w=0.f,h=0.f; int p=0;
    if (tid < G){
      p = pos[slot*MAXGT + tid];
      const float* r = T + (size_t)p*CC;
      x=r[0]; y=r[1]; w=r[2]; h=r[3];
    }
    gp[tid]=p; gx[tid]=x; gy[tid]=y; gw[tid]=w; gh[tid]=h;
    tb[tid]   = make_float4(x-w*0.5f, y-h*0.5f, x+w*0.5f, y+h*0.5f);
    area[tid] = w*h;
  }
  __syncthreads();
  float loss = 0.0f;
  const float inv = 1.0f/(float)LSZ;
  if (z == 0 && tid < G){
    const int n = bn[tid];
    const int a = n/L2, rem = n - a*L2, i = rem/LSZ, j = rem - i*LSZ;
    const float* bp = P + (size_t)a*CC*L2 + rem;
    const float q0=bp[0], q1=bp[L2], q2=bp[2*L2], q3=bp[3*L2], q4=bp[4*L2];
    const float px = ((float)j + sigmoidf(q0))*inv;
    const float py = ((float)i + sigmoidf(q1))*inv;
    const float pw = d_anch[S][a][0]*__expf(q2);
    const float ph = d_anch[S][a][1]*__expf(q3);
    const float dx=px-gx[tid], dy=py-gy[tid], dw=pw-gw[tid], dh=ph-gh[tid];
    loss += (dx*dx+dy*dy+dw*dw+dh*dh)*(2.0f - gw[tid]*gh[tid]);  // reg
    loss += bcef(sigmoidf(q4), 1.0f);                             // conf(obj)
    // subtract bce(conf,0) once per UNIQUE best index if counted in noobj
    bool first = true;
    for (int g2=0; g2<tid; g2++) if (bn[g2]==n) first=false;
    if (first){
      const float bx0=px-pw*0.5f, bx1=px+pw*0.5f, by0=py-ph*0.5f, by1=py+ph*0.5f;
      const float parea = pw*ph;
      float maxiou = 0.0f;
      for (int g2=0; g2<MAXGT; g2++){
        const float4 t4 = tb[g2];
        const float w = fmaxf(fminf(t4.z,bx1) - fmaxf(t4.x,bx0), 0.0f);
        const float h = fmaxf(fminf(t4.w,by1) - fmaxf(t4.y,by0), 0.0f);
        const float inter = w*h;
        maxiou = fmaxf(maxiou, inter / fmaxf(area[g2]+parea-inter, 1e-6f));
      }
      if (maxiou < IGNORE_T) loss -= bcef(sigmoidf(q4), 0.0f);
    }
  }
  if (z == 0 && tid == 0){
    #pragma unroll
    for (int c=0; c<NCH; c++) loss += nob[slot*NCHMAX + c];
  }
  // class loss: G*80 scattered gathers interleaved across the 2 z-blocks
  for (int idx = z*256 + tid; idx < G*NC; idx += 512){
    const int g = idx/NC, c = idx - g*NC;
    const int n = bn[g];
    const int a = n/L2, rem = n - a*L2;
    const float q  = P[(size_t)a*CC*L2 + (size_t)(5+c)*L2 + rem];
    const float tc = T[(size_t)gp[g]*CC + 5 + c];
    loss += bcef(sigmoidf(q), tc);
  }
  __shared__ float wsum[4];
  for (int off=32; off>0; off>>=1) loss += __shfl_down(loss, off, 64);
  if ((tid&63)==0) wsum[tid>>6] = loss;
  __syncthreads();
  if (tid==0) part[slot*2 + z] = wsum[0]+wsum[1]+wsum[2]+wsum[3];  // unconditional
}

__global__ __launch_bounds__(256)
void k_final(const float* __restrict__ p0, const float* __restrict__ t0,
             const float* __restrict__ p1, const float* __restrict__ t1,
             const float* __restrict__ p2, const float* __restrict__ t2,
             const int* __restrict__ cnt, const int* __restrict__ pos,
             const unsigned long long* __restrict__ keys,
             const float* __restrict__ nob, float* __restrict__ part){
  const int b = blockIdx.x, s = blockIdx.y, z = blockIdx.z;
  if (s==0)      final_one<13,0,1>(p0, t0, b, z, cnt, pos, keys, nob, part);
  else if (s==1) final_one<26,1,2>(p1, t1, b, z, cnt, pos, keys, nob, part);
  else           final_one<52,2,8>(p2, t2, b, z, cnt, pos, keys, nob, part);
}

// ---- kernel 3: 384 partials -> out, plain store (no d_out memset needed)
__global__ __launch_bounds__(384)
void k_sum(const float* __restrict__ part, float* __restrict__ out){
  const int tid = threadIdx.x;
  float v = part[tid];
  for (int off=32; off>0; off>>=1) v += __shfl_down(v, off, 64);
  __shared__ float w[6];
  if ((tid&63)==0) w[tid>>6] = v;
  __syncthreads();
  if (tid==0){
    float s = 0.f;
    #pragma unroll
    for (int i=0; i<6; i++) s += w[i];
    out[0] = s;
  }
}

extern "C" void kernel_launch(void* const* d_in, const int* in_sizes, int n_in,
                              void* d_out, int out_size, void* d_ws, size_t ws_size,
                              hipStream_t stream)
{
  // setup_inputs() dict order: pred0, targets0, pred1, targets1, pred2, targets2
  const float* p0 = (const float*)d_in[0];
  const float* t0 = (const float*)d_in[1];
  const float* p1 = (const float*)d_in[2];
  const float* t1 = (const float*)d_in[3];
  const float* p2 = (const float*)d_in[4];
  const float* t2 = (const float*)d_in[5];
  char* ws = (char*)d_ws;
  int*                ws_cnt  = (int*)(ws);
  int*                ws_pos  = (int*)(ws + POS_OFF);
  unsigned long long* ws_keys = (unsigned long long*)(ws + KEY_OFF);
  float*              ws_nob  = (float*)(ws + NOB_OFF);
  float*              ws_part = (float*)(ws + PART_OFF);

  hipMemsetAsync(ws_cnt, 0, CNT_B, stream);          // only cnt needs zeroing

  k_scan <<<2048, 256, 0, stream>>>((const float4*)t0, (const float4*)t1,
                                    (const float4*)t2, ws_cnt, ws_pos);
  k_iou  <<<dim3(NCHMAX,BSZ,3), 256, 0, stream>>>(p0,t0,p1,t1,p2,t2,
                                                  ws_cnt, ws_pos, ws_keys, ws_nob);
  k_final<<<dim3(BSZ,3,2), 256, 0, stream>>>(p0,t0,p1,t1,p2,t2,
                                             ws_cnt, ws_pos, ws_keys, ws_nob, ws_part);
  k_sum  <<<1, 384, 0, stream>>>(ws_part, (float*)d_out);
}

// Round 6
// 390.434 us; speedup vs baseline: 1.5985x; 1.0547x over previous
//
#include <hip/hip_runtime.h>

#define CC 85
#define NC 80
#define MAXGT 20
#define BSZ 64
#define IGNORE_T 0.5f
#define CHUNK 1024
#define NCHMAX 8

// rows per sample per scale: 3*lsz*lsz
#define N0 507
#define N1 2028
#define N2 8112
#define R0 (BSZ*N0)   /* 32448  */
#define R1 (BSZ*N1)   /* 129792 */
#define R2 (BSZ*N2)   /* 519168 */
#define RTOT (R0+R1+R2)

// active iou chunk-blocks per sample: 1 (s0) + 2 (s1) + 8 (s2)
#define CH_PER_B 11

// ws layout (bytes). Only cnt needs zero-init (768 B memset). Everything
// else is written unconditionally before being read (poison-proof).
// NO device-scope fences anywhere (R4 lesson: __threadfence on gfx950's
// non-coherent XCD L2s = flush storm, +290us). Cross-dispatch visibility
// comes free from stream ordering.
#define CNT_B    (192u*4u)                 /* int cnt[192]                  */
#define POS_OFF  CNT_B                     /* int pos[192][20]              */
#define POS_B    (192u*MAXGT*4u)
#define KEY_OFF  (POS_OFF+POS_B)           /* u64 keys[192][8][20], 8-align */
#define KEY_B    (192u*NCHMAX*MAXGT*8u)
#define NOB_OFF  (KEY_OFF+KEY_B)           /* float nob[192][8]             */

// ANCH_REV[l] = ANCHORS[2-l]
__constant__ float d_anch[3][3][2] = {
  {{0.2788f,0.2163f},{0.375f,0.476f},{0.8966f,0.7837f}},  // scale 0, lsz=13
  {{0.0721f,0.1466f},{0.149f,0.1082f},{0.1418f,0.2861f}}, // scale 1, lsz=26
  {{0.024f,0.0313f},{0.0385f,0.0721f},{0.0793f,0.0553f}}, // scale 2, lsz=52
};

__device__ __forceinline__ float sigmoidf(float x){ return 1.0f/(1.0f+__expf(-x)); }
__device__ __forceinline__ float bcef(float p, float t){
  p = fminf(fmaxf(p, 1e-7f), 1.0f-1e-7f);
  return -t*__logf(p) - (1.0f-t)*__logf(1.0f-p);
}

// ---- kernel 0: strided conf scan (R3-proven faster than the 232MB
// coalesced stream: both sit at the ~40us DRAM-line floor, strided won
// the A/B 402.9 vs 411.8). One 4B load per 340B row. Also zeroes out[0]
// for k_final's atomicAdds two dispatches later.
template<int N>
__device__ __forceinline__ void scan_one(const float* __restrict__ tgt, int rl,
                                         int s, int* __restrict__ cnt,
                                         int* __restrict__ pos){
  int b = rl / N;                 // compile-time divisor
  int n = rl - b*N;
  if (tgt[(size_t)rl*CC + 4] > 0.5f){
    int slot = s*BSZ + b;
    int i = atomicAdd(&cnt[slot], 1);
    if (i < MAXGT) pos[slot*MAXGT + i] = n;   // order-irrelevant (all terms
  }                                           // are per-GT sums; dedup only
}                                             // needs uniqueness)

__global__ __launch_bounds__(256)
void k_scan(const float* __restrict__ t0, const float* __restrict__ t1,
            const float* __restrict__ t2,
            int* __restrict__ cnt, int* __restrict__ pos,
            float* __restrict__ out){
  int r = blockIdx.x*256 + threadIdx.x;
  if (r == 0) out[0] = 0.0f;
  if (r < R0)         scan_one<N0>(t0, r,       0, cnt, pos);
  else if (r < R0+R1) scan_one<N1>(t1, r-R0,    1, cnt, pos);
  else if (r < RTOT)  scan_one<N2>(t2, r-R0-R1, 2, cnt, pos);
}

// ---- kernel 1: inline decode + 20-way IoU argmax keys + noobj per chunk.
// Flattened 1D grid: exactly 704 active blocks (was 1536 with 832 inert).
// No atomics, no fences. __launch_bounds__(256,2): key[20] (40 VGPR) must
// stay in registers (default cap spills -> scratch storm).
template<int LSZ, int S>
__device__ __forceinline__ void iou_one(const float* __restrict__ pred,
                                        const float* __restrict__ tgt,
                                        int b, int chunk,
                                        const int* __restrict__ cnt,
                                        const int* __restrict__ pos,
                                        unsigned long long* __restrict__ keys,
                                        float* __restrict__ nob){
  constexpr int L2 = LSZ*LSZ, N = 3*L2;
  const int n0 = chunk*CHUNK;
  const int slot = S*BSZ + b;
  const float* P = pred + (size_t)b*3*CC*L2;
  const float* T = tgt  + (size_t)b*N*CC;
  const int tid = threadIdx.x;
  __shared__ float4 tb[MAXGT];
  __shared__ float  area[MAXGT];
  __shared__ unsigned long long lkey[4][MAXGT];
  __shared__ float  lnob[4];
  if (tid < MAXGT){
    int G = min(cnt[slot], MAXGT);
    float x=0.f,y=0.f,w=0.f,h=0.f;
    if (tid < G){
      const float* r = T + (size_t)pos[slot*MAXGT+tid]*CC;
      x=r[0]; y=r[1]; w=r[2]; h=r[3];
    }
    tb[tid]   = make_float4(x-w*0.5f, y-h*0.5f, x+w*0.5f, y+h*0.5f);
    area[tid] = w*h;                         // zero box -> iou==0 (gmask filler)
  }
  __syncthreads();
  unsigned long long key[MAXGT];
  #pragma unroll
  for (int g=0; g<MAXGT; g++) key[g]=0ull;
  float noobj = 0.0f;
  const float inv = 1.0f/(float)LSZ;
  const int nend = min(n0+CHUNK, N);
  for (int n = n0+tid; n < nend; n += 256){
    const int a = n/L2, rem = n - a*L2, ii = rem/LSZ, jj = rem - ii*LSZ;
    const float* bp = P + (size_t)a*CC*L2 + rem;     // coalesced per channel
    const float q0=bp[0], q1=bp[L2], q2=bp[2*L2], q3=bp[3*L2], q4=bp[4*L2];
    const float px = ((float)jj + sigmoidf(q0))*inv;
    const float py = ((float)ii + sigmoidf(q1))*inv;
    const float pw = d_anch[S][a][0]*__expf(q2);
    const float ph = d_anch[S][a][1]*__expf(q3);
    const float x0=px-pw*0.5f, x1=px+pw*0.5f, y0=py-ph*0.5f, y1=py+ph*0.5f;
    const float pa = pw*ph;
    float maxi = 0.0f;
    const unsigned long long nin = (unsigned long long)(~(unsigned)n); // tie: first
    #pragma unroll
    for (int g=0; g<MAXGT; g++){
      const float4 t4 = tb[g];               // broadcast ds_read_b128
      const float w = fmaxf(fminf(t4.z,x1) - fmaxf(t4.x,x0), 0.0f);
      const float h = fmaxf(fminf(t4.w,y1) - fmaxf(t4.y,y0), 0.0f);
      const float inter = w*h;
      const float io = inter / fmaxf(area[g]+pa-inter, 1e-6f);
      maxi = fmaxf(maxi, io);
      const unsigned long long k =
        ((unsigned long long)__float_as_uint(io)<<32) | nin;
      if (k > key[g]) key[g] = k;
    }
    if (maxi < IGNORE_T) noobj += bcef(sigmoidf(q4), 0.0f);
  }
  const int wid = tid>>6, lane = tid&63;
  #pragma unroll
  for (int g=0; g<MAXGT; g++){
    unsigned long long k = key[g];
    for (int off=32; off>0; off>>=1){
      const unsigned long long o = __shfl_down(k, off, 64);
      if (o > k) k = o;
    }
    if (lane==0) lkey[wid][g] = k;
  }
  for (int off=32; off>0; off>>=1) noobj += __shfl_down(noobj, off, 64);
  if (lane==0) lnob[wid] = noobj;
  __syncthreads();
  if (tid < MAXGT){
    unsigned long long k = lkey[0][tid];
    #pragma unroll
    for (int w=1; w<4; w++){ const unsigned long long o = lkey[w][tid]; if (o>k) k=o; }
    keys[((size_t)slot*NCHMAX + chunk)*MAXGT + tid] = k;   // unconditional
  }
  if (tid==0) nob[slot*NCHMAX + chunk] = lnob[0]+lnob[1]+lnob[2]+lnob[3];
}

__global__ __launch_bounds__(256, 2)
void k_iou(const float* __restrict__ p0, const float* __restrict__ t0,
           const float* __restrict__ p1, const float* __restrict__ t1,
           const float* __restrict__ p2, const float* __restrict__ t2,
           const int* __restrict__ cnt, const int* __restrict__ pos,
           unsigned long long* __restrict__ keys, float* __restrict__ nob){
  // flattened: 64 samples x 11 active chunks (1 s0 + 2 s1 + 8 s2)
  const int bi = blockIdx.x;
  const int b = bi / CH_PER_B;
  const int t = bi - b*CH_PER_B;
  if (t == 0)      iou_one<13,0>(p0, t0, b, 0,   cnt, pos, keys, nob);
  else if (t < 3)  iou_one<26,1>(p1, t1, b, t-1, cnt, pos, keys, nob);
  else             iou_one<52,2>(p2, t2, b, t-3, cnt, pos, keys, nob);
}

// ---- kernel 2: chunk-max -> bn, then reg/conf/cls + deduped noobj
// correction; block-reduced partial goes straight to atomicAdd(out)
// (fuses the old k_sum; out zeroed by k_scan two dispatches earlier).
template<int LSZ, int S, int NCH>
__device__ __forceinline__ void final_one(const float* __restrict__ pred,
                                          const float* __restrict__ tgt,
                                          int b, int z,
                                          const int* __restrict__ cnt,
                                          const int* __restrict__ pos,
                                          const unsigned long long* __restrict__ keys,
                                          const float* __restrict__ nob,
                                          float* __restrict__ out){
  constexpr int L2 = LSZ*LSZ, N = 3*L2;
  const int slot = S*BSZ + b;
  const float* P = pred + (size_t)b*3*CC*L2;
  const float* T = tgt  + (size_t)b*N*CC;
  const int tid = threadIdx.x;
  __shared__ int bn[MAXGT];
  __shared__ int gp[MAXGT];
  __shared__ float gx[MAXGT], gy[MAXGT], gw[MAXGT], gh[MAXGT];
  __shared__ float4 tb[MAXGT];
  __shared__ float area[MAXGT];
  const int G = min(cnt[slot], MAXGT);
  if (tid < MAXGT){
    unsigned long long k = keys[((size_t)slot*NCHMAX + 0)*MAXGT + tid];
    #pragma unroll
    for (int c=1; c<NCH; c++){
      const unsigned long long o = keys[((size_t)slot*NCHMAX + c)*MAXGT + tid];
      if (o > k) k = o;
    }
    bn[tid] = (int)(~(unsigned)(k & 0xffffffffull));
    float x=0.f,y=0.f,w=0.f,h=0.f; int p=0;
    if (tid < G){
      p = pos[slot*MAXGT + tid];
      const float* r = T + (size_t)p*CC;
      x=r[0]; y=r[1]; w=r[2]; h=r[3];
    }
    gp[tid]=p; gx[tid]=x; gy[tid]=y; gw[tid]=w; gh[tid]=h;
    tb[tid]   = make_float4(x-w*0.5f, y-h*0.5f, x+w*0.5f, y+h*0.5f);
    area[tid] = w*h;
  }
  __syncthreads();
  float loss = 0.0f;
  const float inv = 1.0f/(float)LSZ;
  if (z == 0 && tid < G){
    const int n = bn[tid];
    const int a = n/L2, rem = n - a*L2, i = rem/LSZ, j = rem - i*LSZ;
    const float* bp = P + (size_t)a*CC*L2 + rem;
    const float q0=bp[0], q1=bp[L2], q2=bp[2*L2], q3=bp[3*L2], q4=bp[4*L2];
    const float px = ((float)j + sigmoidf(q0))*inv;
    const float py = ((float)i + sigmoidf(q1))*inv;
    const float pw = d_anch[S][a][0]*__expf(q2);
    const float ph = d_anch[S][a][1]*__expf(q3);
    const float dx=px-gx[tid], dy=py-gy[tid], dw=pw-gw[tid], dh=ph-gh[tid];
    loss += (dx*dx+dy*dy+dw*dw+dh*dh)*(2.0f - gw[tid]*gh[tid]);  // reg
    loss += bcef(sigmoidf(q4), 1.0f);                             // conf(obj)
    // subtract bce(conf,0) once per UNIQUE best index if counted in noobj
    bool first = true;
    for (int g2=0; g2<tid; g2++) if (bn[g2]==n) first=false;
    if (first){
      const float bx0=px-pw*0.5f, bx1=px+pw*0.5f, by0=py-ph*0.5f, by1=py+ph*0.5f;
      const float parea = pw*ph;
      float maxiou = 0.0f;
      for (int g2=0; g2<MAXGT; g2++){
        const float4 t4 = tb[g2];
        const float w = fmaxf(fminf(t4.z,bx1) - fmaxf(t4.x,bx0), 0.0f);
        const float h = fmaxf(fminf(t4.w,by1) - fmaxf(t4.y,by0), 0.0f);
        const float inter = w*h;
        maxiou = fmaxf(maxiou, inter / fmaxf(area[g2]+parea-inter, 1e-6f));
      }
      if (maxiou < IGNORE_T) loss -= bcef(sigmoidf(q4), 0.0f);
    }
  }
  if (z == 0 && tid == 0){
    #pragma unroll
    for (int c=0; c<NCH; c++) loss += nob[slot*NCHMAX + c];
  }
  // class loss: G*80 scattered gathers interleaved across the 2 z-blocks
  for (int idx = z*256 + tid; idx < G*NC; idx += 512){
    const int g = idx/NC, c = idx - g*NC;
    const int n = bn[g];
    const int a = n/L2, rem = n - a*L2;
    const float q  = P[(size_t)a*CC*L2 + (size_t)(5+c)*L2 + rem];
    const float tc = T[(size_t)gp[g]*CC + 5 + c];
    loss += bcef(sigmoidf(q), tc);
  }
  __shared__ float wsum[4];
  for (int off=32; off>0; off>>=1) loss += __shfl_down(loss, off, 64);
  if ((tid&63)==0) wsum[tid>>6] = loss;
  __syncthreads();
  if (tid==0){
    const float v = wsum[0]+wsum[1]+wsum[2]+wsum[3];
    if (v != 0.0f || (z == 0)) atomicAdd(out, v);   // skip no-op adds
  }
}

__global__ __launch_bounds__(256)
void k_final(const float* __restrict__ p0, const float* __restrict__ t0,
             const float* __restrict__ p1, const float* __restrict__ t1,
             const float* __restrict__ p2, const float* __restrict__ t2,
             const int* __restrict__ cnt, const int* __restrict__ pos,
             const unsigned long long* __restrict__ keys,
             const float* __restrict__ nob, float* __restrict__ out){
  const int b = blockIdx.x, s = blockIdx.y, z = blockIdx.z;
  if (s==0)      final_one<13,0,1>(p0, t0, b, z, cnt, pos, keys, nob, out);
  else if (s==1) final_one<26,1,2>(p1, t1, b, z, cnt, pos, keys, nob, out);
  else           final_one<52,2,8>(p2, t2, b, z, cnt, pos, keys, nob, out);
}

extern "C" void kernel_launch(void* const* d_in, const int* in_sizes, int n_in,
                              void* d_out, int out_size, void* d_ws, size_t ws_size,
                              hipStream_t stream)
{
  // setup_inputs() dict order: pred0, targets0, pred1, targets1, pred2, targets2
  const float* p0 = (const float*)d_in[0];
  const float* t0 = (const float*)d_in[1];
  const float* p1 = (const float*)d_in[2];
  const float* t1 = (const float*)d_in[3];
  const float* p2 = (const float*)d_in[4];
  const float* t2 = (const float*)d_in[5];
  char* ws = (char*)d_ws;
  int*                ws_cnt  = (int*)(ws);
  int*                ws_pos  = (int*)(ws + POS_OFF);
  unsigned long long* ws_keys = (unsigned long long*)(ws + KEY_OFF);
  float*              ws_nob  = (float*)(ws + NOB_OFF);
  float*              out     = (float*)d_out;

  hipMemsetAsync(ws_cnt, 0, CNT_B, stream);          // only cnt needs zeroing

  k_scan <<<(RTOT+255)/256, 256, 0, stream>>>(t0,t1,t2, ws_cnt, ws_pos, out);
  k_iou  <<<BSZ*CH_PER_B, 256, 0, stream>>>(p0,t0,p1,t1,p2,t2,
                                            ws_cnt, ws_pos, ws_keys, ws_nob);
  k_final<<<dim3(BSZ,3,2), 256, 0, stream>>>(p0,t0,p1,t1,p2,t2,
                                             ws_cnt, ws_pos, ws_keys, ws_nob, out);
}